// Round 3
// baseline (103.769 us; speedup 1.0000x reference)
//
#include <hip/hip_runtime.h>

#define BB 8
#define NN 4096
#define BLK 256
#define NPTS (2*BB*NN)            // 65536 packed points
#define JSL 1024                  // targets per wave (4 waves/block)
#define PK_PAD 8                  // float4 overrun pad for the prefetch tail
#define PARTIAL_OFF 0x110000      // byte offset of partial[] in ws (past pk+pad)

// Pre-pack both clouds as (x, y, z, 0.5*|p|^2) float4 -> ws.
// pk[0..32767] = src points, pk[32768..65535] = tgt points (b-major).
__global__ __launch_bounds__(BLK) void cd_pack(const float* __restrict__ src,
                                               const float* __restrict__ tgt,
                                               float4* __restrict__ pk) {
    int i = blockIdx.x * BLK + threadIdx.x;      // 0..65535
    const float* p = ((i >> 15) ? tgt : src) + 3 * (i & 32767);
    float x = p[0], y = p[1], z = p[2];
    pk[i] = make_float4(x, y, z, 0.5f * (x*x + y*y + z*z));
}

// Block = (dir, batch, 128-row tile). Wave w scans targets [w*1024, w*1024+1024).
// Targets are wave-uniform -> s_load into SGPRs; inner loop is pure VALU:
// acc = 0.5|t|^2 - <s,t>  (3 v_fma, t components as the 1 SGPR operand) + v_min.
// Row-constant 0.5|s|^2 is added after the min (min is shift-invariant).
__global__ __launch_bounds__(BLK) void cd_scan(const float4* __restrict__ pk,
                                               float* __restrict__ partial) {
    __shared__ float pm[4][128];
    __shared__ float bs[4];
    const int dir = blockIdx.z;                  // 0: src->tgt, 1: tgt->src
    const int b   = blockIdx.y;
    const int rt  = blockIdx.x;
    const int tid = threadIdx.x, lane = tid & 63, wave = tid >> 6;

    const float4* S = pk + (dir ? (size_t)BB*NN : 0) + (size_t)b*NN;
    const float4* T = pk + (dir ? 0 : (size_t)BB*NN) + (size_t)b*NN;

    // Two source rows per thread (coalesced dwordx4).
    float4 s0 = S[rt*128 + lane];
    float4 s1 = S[rt*128 + 64 + lane];
    float nx0 = -s0.x, ny0 = -s0.y, nz0 = -s0.z, q0 = s0.w;
    float nx1 = -s1.x, ny1 = -s1.y, nz1 = -s1.z, q1 = s1.w;

    // Force wave-uniform target base -> scalar loads.
    const int jbase = __builtin_amdgcn_readfirstlane(wave * JSL);
    const float4* Tw = T + jbase;

    float m0 = 1.0e30f, m1 = 1.0e30f;
    // 4-deep scalar prefetch; tail overruns by 4 float4 (covered by PK_PAD).
    float4 t0 = Tw[0], t1 = Tw[1], t2 = Tw[2], t3 = Tw[3];
    for (int j = 0; j < JSL; j += 4) {
        float4 n0 = Tw[j+4], n1 = Tw[j+5], n2 = Tw[j+6], n3 = Tw[j+7];
        float a00 = fmaf(nx0, t0.x, fmaf(ny0, t0.y, fmaf(nz0, t0.z, t0.w)));
        float a10 = fmaf(nx1, t0.x, fmaf(ny1, t0.y, fmaf(nz1, t0.z, t0.w)));
        float a01 = fmaf(nx0, t1.x, fmaf(ny0, t1.y, fmaf(nz0, t1.z, t1.w)));
        float a11 = fmaf(nx1, t1.x, fmaf(ny1, t1.y, fmaf(nz1, t1.z, t1.w)));
        float a02 = fmaf(nx0, t2.x, fmaf(ny0, t2.y, fmaf(nz0, t2.z, t2.w)));
        float a12 = fmaf(nx1, t2.x, fmaf(ny1, t2.y, fmaf(nz1, t2.z, t2.w)));
        float a03 = fmaf(nx0, t3.x, fmaf(ny0, t3.y, fmaf(nz0, t3.z, t3.w)));
        float a13 = fmaf(nx1, t3.x, fmaf(ny1, t3.y, fmaf(nz1, t3.z, t3.w)));
        m0 = fminf(fminf(fminf(m0, a00), a01), fminf(a02, a03));
        m1 = fminf(fminf(fminf(m1, a10), a11), fminf(a12, a13));
        t0 = n0; t1 = n1; t2 = n2; t3 = n3;
    }

    pm[wave][lane]      = m0 + q0;   // full d^2/2 for row rt*128+lane
    pm[wave][64 + lane] = m1 + q1;   // row rt*128+64+lane
    __syncthreads();

    float d = 0.0f;
    if (tid < 128) {
        float v = fminf(fminf(pm[0][tid], pm[1][tid]),
                        fminf(pm[2][tid], pm[3][tid]));
        v = fmaxf(v, 0.0f);          // clamp fp rounding negatives
        d = sqrtf(2.0f * v);
    }
#pragma unroll
    for (int o = 32; o > 0; o >>= 1) d += __shfl_down(d, o, 64);
    if (lane == 0) bs[wave] = d;
    __syncthreads();
    if (tid == 0)
        partial[((size_t)dir*BB + b)*32 + rt] = bs[0] + bs[1] + bs[2] + bs[3];
}

__global__ __launch_bounds__(512) void cd_final(const float* __restrict__ partial,
                                                float* __restrict__ out) {
    __shared__ float ps[8];
    float v = partial[threadIdx.x];
#pragma unroll
    for (int o = 32; o > 0; o >>= 1) v += __shfl_down(v, o, 64);
    if ((threadIdx.x & 63) == 0) ps[threadIdx.x >> 6] = v;
    __syncthreads();
    if (threadIdx.x == 0) {
        float t = 0.0f;
#pragma unroll
        for (int w = 0; w < 8; ++w) t += ps[w];
        out[0] = t * (1.0f / (float)(BB * NN));   // mean(term1) + mean(term2)
    }
}

extern "C" void kernel_launch(void* const* d_in, const int* in_sizes, int n_in,
                              void* d_out, int out_size, void* d_ws, size_t ws_size,
                              hipStream_t stream) {
    const float* src = (const float*)d_in[0];
    const float* tgt = (const float*)d_in[1];
    float4* pk = (float4*)d_ws;                              // 1 MB + pad
    float* partial = (float*)((char*)d_ws + PARTIAL_OFF);    // 512 floats
    float* out = (float*)d_out;

    cd_pack<<<NPTS / BLK, BLK, 0, stream>>>(src, tgt, pk);
    dim3 grid(NN / 128, BB, 2);                              // 32 x 8 x 2 = 512
    cd_scan<<<grid, BLK, 0, stream>>>(pk, partial);
    cd_final<<<1, 512, 0, stream>>>(partial, out);
}

// Round 4
// 103.305 us; speedup vs baseline: 1.0045x; 1.0045x over previous
//
#include <hip/hip_runtime.h>

#define BB 8
#define NN 4096
#define BLK 256
#define NPTS (2*BB*NN)            // 65536 packed points
#define JSL 1024                  // targets per wave (4 waves/block)
#define PARTIAL_OFF 0x110000      // byte offset of partial[] in ws (past pk + pad)

// Pre-pack both clouds as (x, y, z, 0.5*|p|^2) float4 -> ws.
// pk[0..32767] = src points, pk[32768..65535] = tgt points (b-major).
__global__ __launch_bounds__(BLK) void cd_pack(const float* __restrict__ src,
                                               const float* __restrict__ tgt,
                                               float4* __restrict__ pk) {
    int i = blockIdx.x * BLK + threadIdx.x;      // 0..65535
    const float* p = ((i >> 15) ? tgt : src) + 3 * (i & 32767);
    float x = p[0], y = p[1], z = p[2];
    pk[i] = make_float4(x, y, z, 0.5f * (x*x + y*y + z*z));
}

// Block = (dir, batch, 128-row tile). Wave w scans targets [w*1024, (w+1)*1024).
// Targets are wave-uniform -> s_load into SGPRs; inner loop is pure VALU.
// Unroll-8 + 8-deep prefetch: 64 VALU instrs (128 cyc) per iteration covers
// the ~200 cyc L2 s_load latency with 2 waves/SIMD (128 own + 128 sibling).
__global__ __launch_bounds__(BLK) void cd_scan(const float4* __restrict__ pk,
                                               float* __restrict__ partial) {
    __shared__ float pm[4][128];
    __shared__ float bs[4];
    const int dir = blockIdx.z;                  // 0: src->tgt, 1: tgt->src
    const int b   = blockIdx.y;
    const int rt  = blockIdx.x;
    const int tid = threadIdx.x, lane = tid & 63, wave = tid >> 6;

    const float4* S = pk + (dir ? (size_t)BB*NN : 0) + (size_t)b*NN;
    const float4* T = pk + (dir ? 0 : (size_t)BB*NN) + (size_t)b*NN;

    // Two source rows per thread (coalesced dwordx4).
    float4 s0 = S[rt*128 + lane];
    float4 s1 = S[rt*128 + 64 + lane];
    float nx0 = -s0.x, ny0 = -s0.y, nz0 = -s0.z, q0 = s0.w;
    float nx1 = -s1.x, ny1 = -s1.y, nz1 = -s1.z, q1 = s1.w;

    // Force wave-uniform target base -> scalar loads.
    const int jbase = __builtin_amdgcn_readfirstlane(wave * JSL);
    const float4* Tw = T + jbase;

    float m0 = 1.0e30f, m1 = 1.0e30f;
    // 8-deep prefetch; final iteration's prefetch overruns by 8 float4
    // (lands in the pad region before PARTIAL_OFF; values never consumed).
    float4 c0 = Tw[0], c1 = Tw[1], c2 = Tw[2], c3 = Tw[3];
    float4 c4 = Tw[4], c5 = Tw[5], c6 = Tw[6], c7 = Tw[7];
    for (int j = 0; j < JSL; j += 8) {
        float4 n0 = Tw[j+8],  n1 = Tw[j+9],  n2 = Tw[j+10], n3 = Tw[j+11];
        float4 n4 = Tw[j+12], n5 = Tw[j+13], n6 = Tw[j+14], n7 = Tw[j+15];

        float a00 = fmaf(nx0, c0.x, fmaf(ny0, c0.y, fmaf(nz0, c0.z, c0.w)));
        float a01 = fmaf(nx0, c1.x, fmaf(ny0, c1.y, fmaf(nz0, c1.z, c1.w)));
        float a02 = fmaf(nx0, c2.x, fmaf(ny0, c2.y, fmaf(nz0, c2.z, c2.w)));
        float a03 = fmaf(nx0, c3.x, fmaf(ny0, c3.y, fmaf(nz0, c3.z, c3.w)));
        float a04 = fmaf(nx0, c4.x, fmaf(ny0, c4.y, fmaf(nz0, c4.z, c4.w)));
        float a05 = fmaf(nx0, c5.x, fmaf(ny0, c5.y, fmaf(nz0, c5.z, c5.w)));
        float a06 = fmaf(nx0, c6.x, fmaf(ny0, c6.y, fmaf(nz0, c6.z, c6.w)));
        float a07 = fmaf(nx0, c7.x, fmaf(ny0, c7.y, fmaf(nz0, c7.z, c7.w)));

        float a10 = fmaf(nx1, c0.x, fmaf(ny1, c0.y, fmaf(nz1, c0.z, c0.w)));
        float a11 = fmaf(nx1, c1.x, fmaf(ny1, c1.y, fmaf(nz1, c1.z, c1.w)));
        float a12 = fmaf(nx1, c2.x, fmaf(ny1, c2.y, fmaf(nz1, c2.z, c2.w)));
        float a13 = fmaf(nx1, c3.x, fmaf(ny1, c3.y, fmaf(nz1, c3.z, c3.w)));
        float a14 = fmaf(nx1, c4.x, fmaf(ny1, c4.y, fmaf(nz1, c4.z, c4.w)));
        float a15 = fmaf(nx1, c5.x, fmaf(ny1, c5.y, fmaf(nz1, c5.z, c5.w)));
        float a16 = fmaf(nx1, c6.x, fmaf(ny1, c6.y, fmaf(nz1, c6.z, c6.w)));
        float a17 = fmaf(nx1, c7.x, fmaf(ny1, c7.y, fmaf(nz1, c7.z, c7.w)));

        float b00 = fminf(a00, a01), b01 = fminf(a02, a03);
        float b02 = fminf(a04, a05), b03 = fminf(a06, a07);
        float b10 = fminf(a10, a11), b11 = fminf(a12, a13);
        float b12 = fminf(a14, a15), b13 = fminf(a16, a17);
        m0 = fminf(m0, fminf(fminf(b00, b01), fminf(b02, b03)));
        m1 = fminf(m1, fminf(fminf(b10, b11), fminf(b12, b13)));

        c0 = n0; c1 = n1; c2 = n2; c3 = n3;
        c4 = n4; c5 = n5; c6 = n6; c7 = n7;
    }

    pm[wave][lane]      = m0 + q0;   // full d^2/2 for row rt*128+lane
    pm[wave][64 + lane] = m1 + q1;   // row rt*128+64+lane
    __syncthreads();

    float d = 0.0f;
    if (tid < 128) {
        float v = fminf(fminf(pm[0][tid], pm[1][tid]),
                        fminf(pm[2][tid], pm[3][tid]));
        v = fmaxf(v, 0.0f);          // clamp fp rounding negatives
        d = sqrtf(2.0f * v);
    }
#pragma unroll
    for (int o = 32; o > 0; o >>= 1) d += __shfl_down(d, o, 64);
    if (lane == 0) bs[wave] = d;
    __syncthreads();
    if (tid == 0)
        partial[((size_t)dir*BB + b)*32 + rt] = bs[0] + bs[1] + bs[2] + bs[3];
}

__global__ __launch_bounds__(512) void cd_final(const float* __restrict__ partial,
                                                float* __restrict__ out) {
    __shared__ float ps[8];
    float v = partial[threadIdx.x];
#pragma unroll
    for (int o = 32; o > 0; o >>= 1) v += __shfl_down(v, o, 64);
    if ((threadIdx.x & 63) == 0) ps[threadIdx.x >> 6] = v;
    __syncthreads();
    if (threadIdx.x == 0) {
        float t = 0.0f;
#pragma unroll
        for (int w = 0; w < 8; ++w) t += ps[w];
        out[0] = t * (1.0f / (float)(BB * NN));   // mean(term1) + mean(term2)
    }
}

extern "C" void kernel_launch(void* const* d_in, const int* in_sizes, int n_in,
                              void* d_out, int out_size, void* d_ws, size_t ws_size,
                              hipStream_t stream) {
    const float* src = (const float*)d_in[0];
    const float* tgt = (const float*)d_in[1];
    float4* pk = (float4*)d_ws;                              // 1 MB + pad
    float* partial = (float*)((char*)d_ws + PARTIAL_OFF);    // 512 floats
    float* out = (float*)d_out;

    cd_pack<<<NPTS / BLK, BLK, 0, stream>>>(src, tgt, pk);
    dim3 grid(NN / 128, BB, 2);                              // 32 x 8 x 2 = 512
    cd_scan<<<grid, BLK, 0, stream>>>(pk, partial);
    cd_final<<<1, 512, 0, stream>>>(partial, out);
}